// Round 1
// baseline (205.669 us; speedup 1.0000x reference)
//
#include <hip/hip_runtime.h>
#include <stdint.h>

#define N_  32
#define C_  128
#define H_  56
#define W_  56
#define HW_ 3136
#define P_  128

using i32x4 = __attribute__((ext_vector_type(4))) int;

// ws layout (bytes):
//   wI8 : P*1152 = 147,456  (i8 +1/-1 weights, [p][tap*128+c])
//   inv : P*4
//   b0  : P*4
#define WI8_BYTES (P_*1152)

// ------- pack weights to i8 +1/-1 in [p][t*128+c] layout; fold BN ------------
__global__ __launch_bounds__(256) void wpack_kernel(const float* __restrict__ weight,
        const float* __restrict__ bias, const float* __restrict__ gamma,
        const float* __restrict__ beta, const float* __restrict__ mean,
        const float* __restrict__ var,
        uint32_t* __restrict__ wI8, float* __restrict__ invG, float* __restrict__ b0G) {
    int gid = blockIdx.x * 256 + threadIdx.x;        // 144 blocks = 36864 dwords
    int p   = gid / 288;
    int rem = gid % 288;
    int k   = rem * 4;                               // k = t*128 + c
    int tp  = k >> 7;
    int c   = k & 127;
    uint32_t d = 0;
    #pragma unroll
    for (int i2 = 0; i2 < 4; ++i2) {
        float v = weight[((size_t)p * C_ + c + i2) * 9 + tp];
        uint32_t by = (v >= 0.f) ? 0x01u : 0xFFu;
        d |= by << (8 * i2);
    }
    wI8[gid] = d;
    if (blockIdx.x == 0 && threadIdx.x < P_) {
        int pp = threadIdx.x;
        float inv = gamma[pp] * rsqrtf(var[pp] + 1e-5f);
        invG[pp] = inv;
        b0G[pp]  = bias[pp] * inv + beta[pp] - mean[pp] * inv;
    }
}

// ------- fused: sign-binarize x in-kernel + binary conv via i8 MFMA + BN + res
// Block: 2 output rows x 64 cols x 128 out-ch. Act tile built directly from x
// (no pack kernel, no abits round-trip). Weights register-stationary
// (double-buffered global prefetch). ONE barrier per block.
// __launch_bounds__(256,4): cap VGPR<=128 -> 4 blocks/CU -> 896-block grid fits
// in a single occupancy round (capacity 1024), no tail.
__global__ __launch_bounds__(256, 4) void bconv_kernel(
        const uint4* __restrict__ wI8v,
        const float* __restrict__ invG, const float* __restrict__ b0G,
        const float* __restrict__ x, float* __restrict__ out) {
    __shared__ uint4 actT[4 * 68 * 8];   // 34816 B: [rho][colL][cblk ^ (colL&7)]
    __shared__ float sInv[P_], sB0[P_];

    int tid = threadIdx.x;
    int img = blockIdx.x / 28;
    int rp  = blockIdx.x % 28;
    int r0  = rp * 2;

    int lane = tid & 63;
    int wi   = tid >> 6;
    int q    = lane >> 4;
    int l15  = lane & 15;
    int m0   = wi * 32;

    if (tid < P_) { sInv[tid] = invG[tid]; sB0[tid] = b0G[tid]; }

    // ---- tap-0 weight prefetch (issue early; independent of expansion) ----
    i32x4 aw[2][2][2];                   // [buf][mi][ks]
    #pragma unroll
    for (int mi = 0; mi < 2; ++mi)
        #pragma unroll
        for (int ks = 0; ks < 2; ++ks)
            aw[0][mi][ks] = *(const i32x4*)&wI8v[(size_t)(m0 + mi*16 + l15) * 72
                                                 + 0 * 8 + ks * 4 + q];

    // ---- expand x signs -> i8 tile (+1/-1, 0 outside image), swizzled ------
    // 224 worker threads: (rho 0..3) x (cg 0..3: 32-ch group) x (tq 0..13: 4 cols)
    // Each loads 32 x float4 (4 adjacent w of one channel), coalesced in 224B
    // runs, extracts sign bits, packs bytes 0x01/0xFF via 0x01010101 + s*0xFE.
    if (tid < 224) {
        int rho = tid / 56;
        int rr  = tid % 56;
        int cg  = rr / 14;               // channel group: c = cg*32 + ci
        int tq  = rr % 14;               // wv0 = tq*4
        int h   = r0 - 1 + rho;
        bool vh = ((unsigned)h < (unsigned)H_);
        uint32_t dwv[4][8];              // [cell k][dword d]; sign bits per byte
        #pragma unroll
        for (int k2 = 0; k2 < 4; ++k2)
            #pragma unroll
            for (int d = 0; d < 8; ++d) dwv[k2][d] = 0;
        if (vh) {
            const uint32_t* xb = (const uint32_t*)x
                + ((size_t)img * C_ + cg * 32) * HW_ + h * W_ + tq * 4;
            #pragma unroll
            for (int ci = 0; ci < 32; ++ci) {
                uint4 u = *(const uint4*)(xb + (size_t)ci * HW_);
                int d  = ci >> 2;
                int sh = (ci & 3) * 8;
                dwv[0][d] |= (u.x >> 31) << sh;
                dwv[1][d] |= (u.y >> 31) << sh;
                dwv[2][d] |= (u.z >> 31) << sh;
                dwv[3][d] |= (u.w >> 31) << sh;
            }
        }
        uint32_t c0 = vh ? 0x01010101u : 0u;   // invalid row -> all-zero bytes
        uint32_t cf = vh ? 0xFEu       : 0u;
        int colL0 = tq * 4 + 1;                // cells colL 1..56 (wv 0..55)
        #pragma unroll
        for (int k2 = 0; k2 < 4; ++k2) {
            int colL = colL0 + k2;
            int base = (rho * 68 + colL) * 8;
            int sz   = colL & 7;
            uint4 lo, hi;
            lo.x = c0 + dwv[k2][0] * cf;  lo.y = c0 + dwv[k2][1] * cf;
            lo.z = c0 + dwv[k2][2] * cf;  lo.w = c0 + dwv[k2][3] * cf;
            hi.x = c0 + dwv[k2][4] * cf;  hi.y = c0 + dwv[k2][5] * cf;
            hi.z = c0 + dwv[k2][6] * cf;  hi.w = c0 + dwv[k2][7] * cf;
            actT[base + ((2 * cg)     ^ sz)] = lo;
            actT[base + ((2 * cg + 1) ^ sz)] = hi;
        }
    } else {
        // 32 threads zero the halo cells: colL==0 and colL 57..67, all 4 rows
        int z = tid - 224;
        #pragma unroll
        for (int rep = 0; rep < 2; ++rep) {
            int e = z + rep * 32;
            if (e < 48) {
                int rho  = e / 12;
                int jj   = e % 12;
                int colL = jj ? (56 + jj) : 0;
                int base = (rho * 68 + colL) * 8;
                #pragma unroll
                for (int s = 0; s < 8; ++s) actT[base + s] = make_uint4(0u,0u,0u,0u);
            }
        }
    }

    i32x4 acc[2][8];
    #pragma unroll
    for (int mi = 0; mi < 2; ++mi)
        #pragma unroll
        for (int j = 0; j < 8; ++j)
            #pragma unroll
            for (int e = 0; e < 4; ++e) acc[mi][j][e] = 0;

    __syncthreads();                     // the ONLY barrier

    for (int t9 = 0; t9 < 9; ++t9) {
        int nb = t9 & 1;
        if (t9 < 8) {                    // prefetch next tap's weights
            #pragma unroll
            for (int mi = 0; mi < 2; ++mi)
                #pragma unroll
                for (int ks = 0; ks < 2; ++ks)
                    aw[nb ^ 1][mi][ks] = *(const i32x4*)&wI8v[(size_t)(m0 + mi*16 + l15) * 72
                                                              + (t9 + 1) * 8 + ks * 4 + q];
        }
        int dh = t9 / 3, dw = t9 % 3;
        #pragma unroll
        for (int ks = 0; ks < 2; ++ks) {
            #pragma unroll
            for (int j = 0; j < 8; ++j) {
                int n    = j * 16 + l15;
                int colL = (n & 63) + dw;
                int rho  = (n >> 6) + dh;
                i32x4 bf = *(const i32x4*)&actT[(rho * 68 + colL) * 8 + ((ks * 4 + q) ^ (colL & 7))];
                acc[0][j] = __builtin_amdgcn_mfma_i32_16x16x64_i8(aw[nb][0][ks], bf, acc[0][j], 0, 0, 0);
                acc[1][j] = __builtin_amdgcn_mfma_i32_16x16x64_i8(aw[nb][1][ks], bf, acc[1][j], 0, 0, 0);
            }
        }
    }

    // ---- epilogue: BN + residual, coalesced 64B segments ----
    float invR[2][4], b0R[2][4];
    #pragma unroll
    for (int mi = 0; mi < 2; ++mi)
        #pragma unroll
        for (int reg = 0; reg < 4; ++reg) {
            int m = m0 + mi * 16 + q * 4 + reg;
            invR[mi][reg] = sInv[m];
            b0R[mi][reg]  = sB0[m];
        }
    #pragma unroll
    for (int j = 0; j < 8; ++j) {
        int n = j * 16 + l15;
        int w = n & 63;
        if (w < W_) {
            int orow = r0 + (n >> 6);
            size_t pixOff = (size_t)img * P_ * HW_ + (size_t)orow * W_ + w;
            #pragma unroll
            for (int mi = 0; mi < 2; ++mi)
                #pragma unroll
                for (int reg = 0; reg < 4; ++reg) {
                    int m = m0 + mi * 16 + q * 4 + reg;
                    size_t off = pixOff + (size_t)m * HW_;
                    out[off] = (float)acc[mi][j][reg] * invR[mi][reg] + b0R[mi][reg] + x[off];
                }
        }
    }
}

extern "C" void kernel_launch(void* const* d_in, const int* in_sizes, int n_in,
                              void* d_out, int out_size, void* d_ws, size_t ws_size,
                              hipStream_t stream) {
    const float* x      = (const float*)d_in[0];
    const float* weight = (const float*)d_in[1];
    const float* bias   = (const float*)d_in[2];
    const float* gamma  = (const float*)d_in[3];
    const float* beta   = (const float*)d_in[4];
    const float* mean   = (const float*)d_in[5];
    const float* var    = (const float*)d_in[6];
    float* out = (float*)d_out;

    uint8_t*  ws    = (uint8_t*)d_ws;
    uint32_t* wI8   = (uint32_t*)ws;
    float*    invG  = (float*)(ws + WI8_BYTES);
    float*    b0G   = invG + P_;

    wpack_kernel<<<144, 256, 0, stream>>>(weight, bias, gamma, beta, mean, var, wI8, invG, b0G);
    bconv_kernel<<<32 * 28, 256, 0, stream>>>((const uint4*)wI8, invG, b0G, x, out);
}

// Round 2
// 146.407 us; speedup vs baseline: 1.4048x; 1.4048x over previous
//
#include <hip/hip_runtime.h>
#include <stdint.h>

#define N_  32
#define C_  128
#define H_  56
#define W_  56
#define HW_ 3136
#define P_  128

using i32x4 = __attribute__((ext_vector_type(4))) int;

// ws layout (bytes):
//   wI8 : P*1152 = 147,456  (i8 +1/-1 weights, [p][tap*128+c])
//   inv : P*4
//   b0  : P*4
#define WI8_BYTES (P_*1152)

// ------- pack weights to i8 +1/-1 in [p][t*128+c] layout; fold BN ------------
__global__ __launch_bounds__(256) void wpack_kernel(const float* __restrict__ weight,
        const float* __restrict__ bias, const float* __restrict__ gamma,
        const float* __restrict__ beta, const float* __restrict__ mean,
        const float* __restrict__ var,
        uint32_t* __restrict__ wI8, float* __restrict__ invG, float* __restrict__ b0G) {
    int gid = blockIdx.x * 256 + threadIdx.x;        // 144 blocks = 36864 dwords
    int p   = gid / 288;
    int rem = gid % 288;
    int k   = rem * 4;                               // k = t*128 + c
    int tp  = k >> 7;
    int c   = k & 127;
    uint32_t d = 0;
    #pragma unroll
    for (int i2 = 0; i2 < 4; ++i2) {
        float v = weight[((size_t)p * C_ + c + i2) * 9 + tp];
        uint32_t by = (v >= 0.f) ? 0x01u : 0xFFu;
        d |= by << (8 * i2);
    }
    wI8[gid] = d;
    if (blockIdx.x == 0 && threadIdx.x < P_) {
        int pp = threadIdx.x;
        float inv = gamma[pp] * rsqrtf(var[pp] + 1e-5f);
        invG[pp] = inv;
        b0G[pp]  = bias[pp] * inv + beta[pp] - mean[pp] * inv;
    }
}

// ------- fused: sign-binarize x in-kernel + binary conv via i8 MFMA + BN + res
// Block: 2 output rows x 64 cols x 128 out-ch. Act tile built directly from x
// (no pack kernel, no abits round-trip). Weights register-stationary
// (double-buffered global prefetch). ONE barrier per block.
// NOTE: __launch_bounds__(256) ONLY. Forcing 4 blocks/CU (R1: (256,4)) squeezes
// arch VGPRs to 64 -> expansion spills to scratch (WRITE_SIZE 232MB, MfmaUtil
// 0.08%). 136-reg / 3 blocks/CU is the working point.
__global__ __launch_bounds__(256) void bconv_kernel(
        const uint4* __restrict__ wI8v,
        const float* __restrict__ invG, const float* __restrict__ b0G,
        const float* __restrict__ x, float* __restrict__ out) {
    __shared__ uint4 actT[4 * 68 * 8];   // 34816 B: [rho][colL][cblk ^ (colL&7)]
    __shared__ float sInv[P_], sB0[P_];

    int tid = threadIdx.x;
    int img = blockIdx.x / 28;
    int rp  = blockIdx.x % 28;
    int r0  = rp * 2;

    int lane = tid & 63;
    int wi   = tid >> 6;
    int q    = lane >> 4;
    int l15  = lane & 15;
    int m0   = wi * 32;

    if (tid < P_) { sInv[tid] = invG[tid]; sB0[tid] = b0G[tid]; }

    // ---- expand x signs -> i8 tile (+1/-1, 0 outside image), swizzled ------
    // 224 worker threads: (rho 0..3) x (cg 0..3: 32-ch group) x (tq 0..13: 4 cols)
    // Each loads 32 x float4 (4 adjacent w of one channel), coalesced in 224B
    // runs, extracts sign bits, packs bytes 0x01/0xFF via 0x01010101 + s*0xFE.
    if (tid < 224) {
        int rho = tid / 56;
        int rr  = tid % 56;
        int cg  = rr / 14;               // channel group: c = cg*32 + ci
        int tq  = rr % 14;               // wv0 = tq*4
        int h   = r0 - 1 + rho;
        bool vh = ((unsigned)h < (unsigned)H_);
        uint32_t dwv[4][8];              // [cell k][dword d]; sign bits per byte
        #pragma unroll
        for (int k2 = 0; k2 < 4; ++k2)
            #pragma unroll
            for (int d = 0; d < 8; ++d) dwv[k2][d] = 0;
        if (vh) {
            const uint32_t* xb = (const uint32_t*)x
                + ((size_t)img * C_ + cg * 32) * HW_ + h * W_ + tq * 4;
            #pragma unroll
            for (int ci = 0; ci < 32; ++ci) {
                uint4 u = *(const uint4*)(xb + (size_t)ci * HW_);
                int d  = ci >> 2;
                int sh = (ci & 3) * 8;
                dwv[0][d] |= (u.x >> 31) << sh;
                dwv[1][d] |= (u.y >> 31) << sh;
                dwv[2][d] |= (u.z >> 31) << sh;
                dwv[3][d] |= (u.w >> 31) << sh;
            }
        }
        uint32_t c0 = vh ? 0x01010101u : 0u;   // invalid row -> all-zero bytes
        uint32_t cf = vh ? 0xFEu       : 0u;
        int colL0 = tq * 4 + 1;                // cells colL 1..56 (wv 0..55)
        #pragma unroll
        for (int k2 = 0; k2 < 4; ++k2) {
            int colL = colL0 + k2;
            int base = (rho * 68 + colL) * 8;
            int sz   = colL & 7;
            uint4 lo, hi;
            lo.x = c0 + dwv[k2][0] * cf;  lo.y = c0 + dwv[k2][1] * cf;
            lo.z = c0 + dwv[k2][2] * cf;  lo.w = c0 + dwv[k2][3] * cf;
            hi.x = c0 + dwv[k2][4] * cf;  hi.y = c0 + dwv[k2][5] * cf;
            hi.z = c0 + dwv[k2][6] * cf;  hi.w = c0 + dwv[k2][7] * cf;
            actT[base + ((2 * cg)     ^ sz)] = lo;
            actT[base + ((2 * cg + 1) ^ sz)] = hi;
        }
    } else {
        // 32 threads zero the halo cells: colL==0 and colL 57..67, all 4 rows
        int z = tid - 224;
        #pragma unroll
        for (int rep = 0; rep < 2; ++rep) {
            int e = z + rep * 32;
            if (e < 48) {
                int rho  = e / 12;
                int jj   = e % 12;
                int colL = jj ? (56 + jj) : 0;
                int base = (rho * 68 + colL) * 8;
                #pragma unroll
                for (int s = 0; s < 8; ++s) actT[base + s] = make_uint4(0u,0u,0u,0u);
            }
        }
    }

    // ---- tap-0 weight prefetch (issued after expansion so aw regs are not
    // live across the expansion's register peak; still overlaps the barrier) --
    i32x4 aw[2][2][2];                   // [buf][mi][ks]
    #pragma unroll
    for (int mi = 0; mi < 2; ++mi)
        #pragma unroll
        for (int ks = 0; ks < 2; ++ks)
            aw[0][mi][ks] = *(const i32x4*)&wI8v[(size_t)(m0 + mi*16 + l15) * 72
                                                 + 0 * 8 + ks * 4 + q];

    i32x4 acc[2][8];
    #pragma unroll
    for (int mi = 0; mi < 2; ++mi)
        #pragma unroll
        for (int j = 0; j < 8; ++j)
            #pragma unroll
            for (int e = 0; e < 4; ++e) acc[mi][j][e] = 0;

    __syncthreads();                     // the ONLY barrier

    for (int t9 = 0; t9 < 9; ++t9) {
        int nb = t9 & 1;
        if (t9 < 8) {                    // prefetch next tap's weights
            #pragma unroll
            for (int mi = 0; mi < 2; ++mi)
                #pragma unroll
                for (int ks = 0; ks < 2; ++ks)
                    aw[nb ^ 1][mi][ks] = *(const i32x4*)&wI8v[(size_t)(m0 + mi*16 + l15) * 72
                                                              + (t9 + 1) * 8 + ks * 4 + q];
        }
        int dh = t9 / 3, dw = t9 % 3;
        #pragma unroll
        for (int ks = 0; ks < 2; ++ks) {
            #pragma unroll
            for (int j = 0; j < 8; ++j) {
                int n    = j * 16 + l15;
                int colL = (n & 63) + dw;
                int rho  = (n >> 6) + dh;
                i32x4 bf = *(const i32x4*)&actT[(rho * 68 + colL) * 8 + ((ks * 4 + q) ^ (colL & 7))];
                acc[0][j] = __builtin_amdgcn_mfma_i32_16x16x64_i8(aw[nb][0][ks], bf, acc[0][j], 0, 0, 0);
                acc[1][j] = __builtin_amdgcn_mfma_i32_16x16x64_i8(aw[nb][1][ks], bf, acc[1][j], 0, 0, 0);
            }
        }
    }

    // ---- epilogue: BN + residual, coalesced 64B segments ----
    float invR[2][4], b0R[2][4];
    #pragma unroll
    for (int mi = 0; mi < 2; ++mi)
        #pragma unroll
        for (int reg = 0; reg < 4; ++reg) {
            int m = m0 + mi * 16 + q * 4 + reg;
            invR[mi][reg] = sInv[m];
            b0R[mi][reg]  = sB0[m];
        }
    #pragma unroll
    for (int j = 0; j < 8; ++j) {
        int n = j * 16 + l15;
        int w = n & 63;
        if (w < W_) {
            int orow = r0 + (n >> 6);
            size_t pixOff = (size_t)img * P_ * HW_ + (size_t)orow * W_ + w;
            #pragma unroll
            for (int mi = 0; mi < 2; ++mi)
                #pragma unroll
                for (int reg = 0; reg < 4; ++reg) {
                    int m = m0 + mi * 16 + q * 4 + reg;
                    size_t off = pixOff + (size_t)m * HW_;
                    out[off] = (float)acc[mi][j][reg] * invR[mi][reg] + b0R[mi][reg] + x[off];
                }
        }
    }
}

extern "C" void kernel_launch(void* const* d_in, const int* in_sizes, int n_in,
                              void* d_out, int out_size, void* d_ws, size_t ws_size,
                              hipStream_t stream) {
    const float* x      = (const float*)d_in[0];
    const float* weight = (const float*)d_in[1];
    const float* bias   = (const float*)d_in[2];
    const float* gamma  = (const float*)d_in[3];
    const float* beta   = (const float*)d_in[4];
    const float* mean   = (const float*)d_in[5];
    const float* var    = (const float*)d_in[6];
    float* out = (float*)d_out;

    uint8_t*  ws    = (uint8_t*)d_ws;
    uint32_t* wI8   = (uint32_t*)ws;
    float*    invG  = (float*)(ws + WI8_BYTES);
    float*    b0G   = invG + P_;

    wpack_kernel<<<144, 256, 0, stream>>>(weight, bias, gamma, beta, mean, var, wI8, invG, b0G);
    bconv_kernel<<<32 * 28, 256, 0, stream>>>((const uint4*)wI8, invG, b0G, x, out);
}